// Round 7
// baseline (251.476 us; speedup 1.0000x reference)
//
#include <hip/hip_runtime.h>
#include <hip/hip_bf16.h>
#include <math.h>

#define NN 200
#define DD 8
#define HH 128
#define NHEAD 4
#define HDIM 32
#define LL 6
#define EE 16384
#define SS 8
#define FFD 512
#define W64 256                  // EE/64 bitmap words per node column

#define WSCALE 1048576.0f        // 2^20 fixed-point scale for LDS int attention atomics
#define WNORM  (1.0f/1048576.0f)
#define RSCALE 0.17677669529663687f   // 1/sqrt(32)

// ---------------- helpers ----------------

__device__ __forceinline__ float geluf(float x) {
    return 0.5f * x * (1.0f + erff(x * 0.70710678118654752f));
}
__device__ __forceinline__ float softplusf(float x) {
    return (x > 20.0f) ? x : log1pf(expf(x));
}
__device__ __forceinline__ void ln_reduce(const float* sv, const float* sv2, float* mred, int tid) {
    if (tid < 64) {
        float s1 = sv[tid] + sv[tid + 64];
        float s2 = sv2[tid] + sv2[tid + 64];
        #pragma unroll
        for (int m = 32; m > 0; m >>= 1) {
            s1 += __shfl_xor(s1, m);
            s2 += __shfl_xor(s2, m);
        }
        if (tid == 0) { mred[0] = s1 * (1.0f / HH); mred[1] = s2 * (1.0f / HH); }
    }
}

// ---------------- setup ----------------

// Each block a scans hedges, builds its own bitmap column, writes bmT (no memset, no global atomics)
__launch_bounds__(1024)
__global__ void k_prepA(const int* __restrict__ hedges, unsigned long long* __restrict__ bmT) {
    __shared__ unsigned long long colA[W64];
    int a = blockIdx.x, tid = threadIdx.x;
    for (int w = tid; w < W64; w += 1024) colA[w] = 0ULL;
    __syncthreads();
    const int4* he4 = (const int4*)hedges;
    for (int i4 = tid; i4 < EE * SS / 4; i4 += 1024) {
        int4 v = he4[i4];
        if (v.x == a || v.y == a || v.z == a || v.w == a) {
            int e = i4 >> 1;
            atomicOr(&colA[e >> 6], 1ULL << (e & 63));
        }
    }
    __syncthreads();
    for (int w = tid; w < W64; w += 1024) bmT[w * NN + a] = colA[w];
}

// Per node a: float G row + member-edge list + count + embed (h0, hc0)
__launch_bounds__(1024)
__global__ void k_prepB(const unsigned long long* __restrict__ bmT,
                        const float* __restrict__ x, const float* __restrict__ Wi,
                        const float* __restrict__ bi, const float* __restrict__ lnig,
                        const float* __restrict__ lnib, const float* __restrict__ Wc0,
                        float* __restrict__ Gf, int* __restrict__ lst, int* __restrict__ cntA,
                        float* __restrict__ h, float* __restrict__ hc) {
    __shared__ unsigned long long colA[W64];
    __shared__ int psG[4][256];
    __shared__ int wsum[4];
    __shared__ float row[HH], sv[HH], sv2[HH], mred[2];
    __shared__ float4 psum4[8][32];
    int a = blockIdx.x, tid = threadIdx.x;
    if (tid < W64) colA[tid] = bmT[tid * NN + a];
    __syncthreads();
    {   // G row popcount, 4-way word split
        int q = tid >> 8, b = tid & 255;
        if (b < NN) {
            int acc = 0, w0 = q * 64;
            #pragma unroll 8
            for (int w = 0; w < 64; ++w) acc += __popcll(colA[w0 + w] & bmT[(w0 + w) * NN + b]);
            psG[q][b] = acc;
        }
    }
    // list extraction prefix-scan on first 256 threads
    unsigned long long w = 0ULL; int c = 0, incl = 0, lane = tid & 63, wid = tid >> 6;
    if (tid < W64) {
        w = colA[tid];
        c = __popcll(w);
        incl = c;
        #pragma unroll
        for (int m = 1; m < 64; m <<= 1) {
            int v = __shfl_up(incl, m);
            if (lane >= m) incl += v;
        }
        if (lane == 63) wsum[wid] = incl;
    }
    __syncthreads();
    if (tid == 0) {
        int ss = 0;
        #pragma unroll
        for (int i = 0; i < 4; ++i) { int v = wsum[i]; wsum[i] = ss; ss += v; }
        cntA[a] = ss;
    }
    if (tid < NN) Gf[a * NN + tid] = (float)(psG[0][tid] + psG[1][tid] + psG[2][tid] + psG[3][tid]);
    __syncthreads();
    if (tid < W64) {
        int base = wsum[wid] + incl - c;
        while (w) {
            int b = __ffsll((long long)w) - 1;
            w &= w - 1;
            lst[a * 1024 + base++] = tid * 64 + b;
        }
    }
    // embed
    float s = 0.0f;
    if (tid < HH) {
        s = bi[tid];
        #pragma unroll
        for (int d = 0; d < DD; ++d) s = fmaf(x[a * DD + d], Wi[d * HH + tid], s);
        sv[tid] = s; sv2[tid] = s * s;
    }
    __syncthreads();
    ln_reduce(sv, sv2, mred, tid);
    __syncthreads();
    if (tid < HH) {
        float mean = mred[0], var = mred[1] - mean * mean;
        float v = (s - mean) * rsqrtf(var + 1e-5f) * lnig[tid] + lnib[tid];
        float ge = geluf(v);
        int i2 = (tid >> 1) * 2;
        float div = expf((float)i2 * (-9.210340371976184f / 128.0f));
        float ang = (float)a * div;
        float pe = (tid & 1) ? cosf(ang) : sinf(ang);
        float hv = ge + pe;
        row[tid] = hv;
        h[a * HH + tid] = hv;
    }
    __syncthreads();
    if (tid < 256) {   // hc0 = row @ Wc0, float4, 8-way split-K
        int kq = tid >> 5, jq = tid & 31, k0 = kq * 16;
        float4 acc = make_float4(0.f, 0.f, 0.f, 0.f);
        #pragma unroll 8
        for (int kk = 0; kk < 16; ++kk) {
            float r = row[k0 + kk];
            float4 wv = *(const float4*)(Wc0 + (k0 + kk) * HH + jq * 4);
            acc.x = fmaf(r, wv.x, acc.x); acc.y = fmaf(r, wv.y, acc.y);
            acc.z = fmaf(r, wv.z, acc.z); acc.w = fmaf(r, wv.w, acc.w);
        }
        psum4[kq][jq] = acc;
    }
    __syncthreads();
    if (tid < HH) {
        const float* pf = (const float*)psum4;
        float acc = 0.0f;
        #pragma unroll
        for (int kq = 0; kq < 8; ++kq) acc += pf[kq * HH + tid];
        hc[a * HH + tid] = acc;
    }
}

// ---------------- layer kernels ----------------

// conv(G@hc) + LN1 + QKV.  grid: 200 x 1024
__launch_bounds__(1024)
__global__ void k_node1(const float* __restrict__ h, const float* __restrict__ hc,
                        const float* __restrict__ Gf, const int* __restrict__ cntA,
                        const float* __restrict__ bc,
                        const float* __restrict__ Wq, const float* __restrict__ bq,
                        const float* __restrict__ Wk, const float* __restrict__ bk,
                        const float* __restrict__ Wv, const float* __restrict__ bv,
                        const float* __restrict__ n1g, const float* __restrict__ n1b,
                        float* __restrict__ h1, float* __restrict__ Qo,
                        float* __restrict__ Ko, float* __restrict__ Vo) {
    int n = blockIdx.x, tid = threadIdx.x;
    __shared__ float Gs[NN];
    __shared__ float row[HH], sv[HH], sv2[HH], mred[2];
    __shared__ float4 psA4[8][32], psB4[8][32], psC4[8][32];
    // prefetch (register) while Gs loads
    float hval = (tid < HH) ? h[n * HH + tid] : 0.0f;
    float cntn = fmaxf((float)cntA[n], 1.0f);
    if (tid < NN) Gs[tid] = Gf[n * NN + tid];
    __syncthreads();
    if (tid < 256) {   // conv float4: 8 kq x 25 rows
        int kq = tid >> 5, jq = tid & 31, m0 = kq * 25;
        float4 acc = make_float4(0.f, 0.f, 0.f, 0.f);
        #pragma unroll 5
        for (int mm = 0; mm < 25; ++mm) {
            float g = Gs[m0 + mm];
            float4 hv = *(const float4*)(hc + (m0 + mm) * HH + jq * 4);
            acc.x = fmaf(g, hv.x, acc.x); acc.y = fmaf(g, hv.y, acc.y);
            acc.z = fmaf(g, hv.z, acc.z); acc.w = fmaf(g, hv.w, acc.w);
        }
        psA4[kq][jq] = acc;
    }
    __syncthreads();
    float val = 0.0f;
    if (tid < HH) {
        const float* pf = (const float*)psA4;
        float acc = 0.0f;
        #pragma unroll
        for (int kq = 0; kq < 8; ++kq) acc += pf[kq * HH + tid];
        val = hval + acc / (8.0f * cntn) + bc[tid];
        sv[tid] = val; sv2[tid] = val * val;
    }
    __syncthreads();
    ln_reduce(sv, sv2, mred, tid);
    __syncthreads();
    if (tid < HH) {
        float mean = mred[0], var = mred[1] - mean * mean;
        float hv = (val - mean) * rsqrtf(var + 1e-5f) * n1g[tid] + n1b[tid];
        row[tid] = hv;
        h1[n * HH + tid] = hv;
    }
    __syncthreads();
    if (tid < 256) {   // QKV float4, 8 kq x 16 k
        int kq = tid >> 5, jq = tid & 31, k0 = kq * 16;
        float4 aq = make_float4(0.f, 0.f, 0.f, 0.f);
        float4 ak = make_float4(0.f, 0.f, 0.f, 0.f);
        float4 av = make_float4(0.f, 0.f, 0.f, 0.f);
        #pragma unroll 4
        for (int kk = 0; kk < 16; ++kk) {
            float r = row[k0 + kk];
            int idx = (k0 + kk) * HH + jq * 4;
            float4 wq = *(const float4*)(Wq + idx);
            float4 wk = *(const float4*)(Wk + idx);
            float4 wv = *(const float4*)(Wv + idx);
            aq.x = fmaf(r, wq.x, aq.x); aq.y = fmaf(r, wq.y, aq.y);
            aq.z = fmaf(r, wq.z, aq.z); aq.w = fmaf(r, wq.w, aq.w);
            ak.x = fmaf(r, wk.x, ak.x); ak.y = fmaf(r, wk.y, ak.y);
            ak.z = fmaf(r, wk.z, ak.z); ak.w = fmaf(r, wk.w, ak.w);
            av.x = fmaf(r, wv.x, av.x); av.y = fmaf(r, wv.y, av.y);
            av.z = fmaf(r, wv.z, av.z); av.w = fmaf(r, wv.w, av.w);
        }
        psA4[kq][jq] = aq; psB4[kq][jq] = ak; psC4[kq][jq] = av;
    }
    __syncthreads();
    if (tid < 384) {
        int wh = tid >> 7, j = tid & 127;
        const float* pf = (const float*)(wh == 0 ? psA4 : (wh == 1 ? psB4 : psC4));
        float acc = 0.0f;
        #pragma unroll
        for (int kq = 0; kq < 8; ++kq) acc += pf[kq * HH + j];
        if (wh == 0)      Qo[n * HH + j] = bq[j] + acc;
        else if (wh == 1) Ko[n * HH + j] = bk[j] + acc;
        else              Vo[n * HH + j] = bv[j] + acc;
    }
}

// attention + Wo + FFN + LN2 + next-layer hc.  grid: 200 x 1024
__launch_bounds__(1024)
__global__ void k_edgefused(const float* __restrict__ Q, const float* __restrict__ K,
                            const float* __restrict__ V, const int* __restrict__ hedges,
                            const int* __restrict__ lst, const int* __restrict__ cntA,
                            const float* __restrict__ h1,
                            const float* __restrict__ Wo, const float* __restrict__ bo,
                            const float* __restrict__ Wf1, const float* __restrict__ bf1,
                            const float* __restrict__ Wf2, const float* __restrict__ bf2,
                            const float* __restrict__ n2g, const float* __restrict__ n2b,
                            const float* __restrict__ WcN,
                            float* __restrict__ h, float* __restrict__ hc) {
    __shared__ float Ts[NHEAD * NN];
    __shared__ int   Wrow[NHEAD * NN];
    __shared__ float4 Qs4[32];
    __shared__ float4 psum4[8][32];
    __shared__ float2 psF2[4][256];
    __shared__ float ts[FFD];
    __shared__ float sv[HH], sv2[HH], mred[2];
    __shared__ float aggs[HH], h2s[HH], rowN[HH];
    float* Qs = (float*)Qs4;

    int a = blockIdx.x, tid = threadIdx.x;
    int cnt = cntA[a];
    float cntn = fmaxf((float)cnt, 1.0f);
    // register prefetch for late phases
    float h1v = 0.0f, bov = 0.0f;
    if (tid < HH) { h1v = h1[a * HH + tid]; bov = bo[tid]; }

    if (tid < HH) Qs[tid] = Q[a * HH + tid];
    if (tid < NHEAD * NN) Wrow[tid] = 0;
    __syncthreads();

    {   // logits Ts[h][b] = (q_a[h].k_b[h]) * RSCALE
        int hh = tid >> 8, b = tid & 255;
        if (b < NN) {
            const float4* kp4 = (const float4*)(K + b * HH + hh * HDIM);
            const float4* qp4 = (const float4*)(Qs + hh * HDIM);
            float acc = 0.0f;
            #pragma unroll
            for (int u = 0; u < 8; ++u) {
                float4 kv = kp4[u], qv = qp4[u];
                acc += qv.x * kv.x + qv.y * kv.y + qv.z * kv.z + qv.w * kv.w;
            }
            Ts[hh * NN + b] = acc * RSCALE;
        }
    }
    __syncthreads();

    // phase A: per (member-edge, head) softmax -> LDS int scatter
    int ntask = cnt * NHEAD;
    const int* lstA = lst + a * 1024;
    for (int t = tid; t < ntask; t += 1024) {
        int m = t >> 2, hh = t & 3;
        int e = lstA[m];
        int4 e0 = ((const int4*)hedges)[e * 2];
        int4 e1 = ((const int4*)hedges)[e * 2 + 1];
        const float* Tr = Ts + hh * NN;
        float l0 = Tr[e0.x], l1 = Tr[e0.y], l2 = Tr[e0.z], l3 = Tr[e0.w];
        float l4 = Tr[e1.x], l5 = Tr[e1.y], l6 = Tr[e1.z], l7 = Tr[e1.w];
        float mx = fmaxf(fmaxf(fmaxf(l0, l1), fmaxf(l2, l3)),
                         fmaxf(fmaxf(l4, l5), fmaxf(l6, l7)));
        l0 = __expf(l0 - mx); l1 = __expf(l1 - mx); l2 = __expf(l2 - mx); l3 = __expf(l3 - mx);
        l4 = __expf(l4 - mx); l5 = __expf(l5 - mx); l6 = __expf(l6 - mx); l7 = __expf(l7 - mx);
        float inv = WSCALE / (l0 + l1 + l2 + l3 + l4 + l5 + l6 + l7);
        int* Wr = Wrow + hh * NN;
        atomicAdd(&Wr[e0.x], __float2int_rn(l0 * inv));
        atomicAdd(&Wr[e0.y], __float2int_rn(l1 * inv));
        atomicAdd(&Wr[e0.z], __float2int_rn(l2 * inv));
        atomicAdd(&Wr[e0.w], __float2int_rn(l3 * inv));
        atomicAdd(&Wr[e1.x], __float2int_rn(l4 * inv));
        atomicAdd(&Wr[e1.y], __float2int_rn(l5 * inv));
        atomicAdd(&Wr[e1.z], __float2int_rn(l6 * inv));
        atomicAdd(&Wr[e1.w], __float2int_rn(l7 * inv));
    }
    __syncthreads();

    if (tid < 256) {   // phase B: agg = Wrow@V, float4, 8 kq x 25 b
        int kq = tid >> 5, jq = tid & 31, hh = jq >> 3, b0 = kq * 25;
        float4 acc = make_float4(0.f, 0.f, 0.f, 0.f);
        #pragma unroll 5
        for (int bb = 0; bb < 25; ++bb) {
            int b = b0 + bb;
            float wv = (float)Wrow[hh * NN + b];
            float4 vv = *(const float4*)(V + b * HH + jq * 4);
            acc.x = fmaf(wv, vv.x, acc.x); acc.y = fmaf(wv, vv.y, acc.y);
            acc.z = fmaf(wv, vv.z, acc.z); acc.w = fmaf(wv, vv.w, acc.w);
        }
        psum4[kq][jq] = acc;
    }
    __syncthreads();
    if (tid < HH) {
        const float* pf = (const float*)psum4;
        float acc = 0.0f;
        #pragma unroll
        for (int kq = 0; kq < 8; ++kq) acc += pf[kq * HH + tid];
        aggs[tid] = acc * WNORM / cntn;
    }
    __syncthreads();
    if (tid < 256) {   // Wo GEMV float4
        int kq = tid >> 5, jq = tid & 31, k0 = kq * 16;
        float4 acc = make_float4(0.f, 0.f, 0.f, 0.f);
        #pragma unroll 8
        for (int kk = 0; kk < 16; ++kk) {
            float r = aggs[k0 + kk];
            float4 wv = *(const float4*)(Wo + (k0 + kk) * HH + jq * 4);
            acc.x = fmaf(r, wv.x, acc.x); acc.y = fmaf(r, wv.y, acc.y);
            acc.z = fmaf(r, wv.z, acc.z); acc.w = fmaf(r, wv.w, acc.w);
        }
        psum4[kq][jq] = acc;
    }
    __syncthreads();
    if (tid < HH) {
        const float* pf = (const float*)psum4;
        float acc = 0.0f;
        #pragma unroll
        for (int kq = 0; kq < 8; ++kq) acc += pf[kq * HH + tid];
        h2s[tid] = h1v + bov + acc;
    }
    __syncthreads();
    {   // FFN1: float2, 4-way split-K (chain 32)
        int kf = tid >> 8, fq = tid & 255, k0 = kf * 32, f = fq * 2;
        float2 acc = make_float2(0.f, 0.f);
        #pragma unroll 8
        for (int kk = 0; kk < 32; ++kk) {
            float r = h2s[k0 + kk];
            float2 wv = *(const float2*)(Wf1 + (k0 + kk) * FFD + f);
            acc.x = fmaf(r, wv.x, acc.x); acc.y = fmaf(r, wv.y, acc.y);
        }
        psF2[kf][fq] = acc;
    }
    __syncthreads();
    if (tid < FFD) {
        const float* pf = (const float*)psF2;
        float acc = bf1[tid];
        #pragma unroll
        for (int kf = 0; kf < 4; ++kf) acc += pf[kf * FFD + tid];
        ts[tid] = geluf(acc);
    }
    __syncthreads();
    if (tid < 256) {   // FFN2 float4, 8 kq x 64 f
        int kq = tid >> 5, jq = tid & 31, f0 = kq * 64;
        float4 acc = make_float4(0.f, 0.f, 0.f, 0.f);
        #pragma unroll 8
        for (int ff = 0; ff < 64; ++ff) {
            float r = ts[f0 + ff];
            float4 wv = *(const float4*)(Wf2 + (f0 + ff) * HH + jq * 4);
            acc.x = fmaf(r, wv.x, acc.x); acc.y = fmaf(r, wv.y, acc.y);
            acc.z = fmaf(r, wv.z, acc.z); acc.w = fmaf(r, wv.w, acc.w);
        }
        psum4[kq][jq] = acc;
    }
    __syncthreads();
    float o = 0.0f;
    if (tid < HH) {
        const float* pf = (const float*)psum4;
        float acc = 0.0f;
        #pragma unroll
        for (int kq = 0; kq < 8; ++kq) acc += pf[kq * HH + tid];
        o = h2s[tid] + bf2[tid] + acc;
        sv[tid] = o; sv2[tid] = o * o;
    }
    __syncthreads();
    ln_reduce(sv, sv2, mred, tid);
    __syncthreads();
    if (tid < HH) {
        float mean = mred[0], var = mred[1] - mean * mean;
        float hv = (o - mean) * rsqrtf(var + 1e-5f) * n2g[tid] + n2b[tid];
        rowN[tid] = hv;
        h[a * HH + tid] = hv;
    }
    __syncthreads();
    if (WcN) {
        if (tid < 256) {
            int kq = tid >> 5, jq = tid & 31, k0 = kq * 16;
            float4 acc = make_float4(0.f, 0.f, 0.f, 0.f);
            #pragma unroll 8
            for (int kk = 0; kk < 16; ++kk) {
                float r = rowN[k0 + kk];
                float4 wv = *(const float4*)(WcN + (k0 + kk) * HH + jq * 4);
                acc.x = fmaf(r, wv.x, acc.x); acc.y = fmaf(r, wv.y, acc.y);
                acc.z = fmaf(r, wv.z, acc.z); acc.w = fmaf(r, wv.w, acc.w);
            }
            psum4[kq][jq] = acc;
        }
        __syncthreads();
        if (tid < HH) {
            const float* pf = (const float*)psum4;
            float acc = 0.0f;
            #pragma unroll
            for (int kq = 0; kq < 8; ++kq) acc += pf[kq * HH + tid];
            hc[a * HH + tid] = acc;
        }
    }
}

// Pool + heads + emb, 4 blocks x 512
__launch_bounds__(512)
__global__ void k_final4(const float* __restrict__ h,
                         const float* __restrict__ Wh1, const float* __restrict__ bh1,
                         const float* __restrict__ Wh2, const float* __restrict__ bh2,
                         const float* __restrict__ Wh3, const float* __restrict__ bh3,
                         const float* __restrict__ We, const float* __restrict__ be,
                         float* __restrict__ out) {
    __shared__ float gs[384];
    __shared__ float pm[4][HH], px[4][HH];
    __shared__ float psum[4][HH];
    __shared__ float t1s[HH];
    __shared__ float t2s[64];
    int tid = threadIdx.x, j = tid & 127, kq = tid >> 7, kb = blockIdx.x;
    {
        float sm = 0.0f, mx = -3.4e38f;
        for (int r = 0; r < 50; ++r) {
            float v = h[(kq * 50 + r) * HH + j];
            sm += v; mx = fmaxf(mx, v);
        }
        pm[kq][j] = sm; px[kq][j] = mx;
    }
    __syncthreads();
    if (tid < HH) {
        float s = pm[0][j] + pm[1][j] + pm[2][j] + pm[3][j];
        float m = fmaxf(fmaxf(px[0][j], px[1][j]), fmaxf(px[2][j], px[3][j]));
        gs[j] = s * (1.0f / NN); gs[HH + j] = m; gs[2 * HH + j] = s;
    }
    __syncthreads();
    if (kb < 3) {
        float p = 0.0f;
        int i0 = kq * 96;
        #pragma unroll 8
        for (int ii = 0; ii < 96; ++ii) p = fmaf(gs[i0 + ii], Wh1[kb * 49152 + (i0 + ii) * 128 + j], p);
        psum[kq][j] = p;
        __syncthreads();
        if (tid < HH) t1s[j] = geluf(bh1[kb * 128 + j] + psum[0][j] + psum[1][j] + psum[2][j] + psum[3][j]);
        __syncthreads();
        if (tid < 256) {
            int o = tid & 63, sc = tid >> 6;
            float p2 = 0.0f;
            int i0b = sc * 32;
            #pragma unroll 8
            for (int ii = 0; ii < 32; ++ii) p2 = fmaf(t1s[i0b + ii], Wh2[kb * 8192 + (i0b + ii) * 64 + o], p2);
            psum[sc][o] = p2;
        }
        __syncthreads();
        if (tid < 64) t2s[tid] = geluf(bh2[kb * 64 + tid] + psum[0][tid] + psum[1][tid] + psum[2][tid] + psum[3][tid]);
        __syncthreads();
        if (tid < 64) {
            float v = t2s[tid] * Wh3[kb * 64 + tid];
            #pragma unroll
            for (int m = 32; m > 0; m >>= 1) v += __shfl_xor(v, m);
            if (tid == 0) {
                float acc = v + bh3[kb];
                float r;
                if (kb == 0)      r = softplusf(acc) + 1.0f;
                else if (kb == 1) r = 1.0f / (1.0f + expf(-acc));
                else              r = softplusf(acc);
                out[kb] = r;
            }
        }
    } else {
        float p = 0.0f;
        int i0 = kq * 96;
        #pragma unroll 8
        for (int ii = 0; ii < 96; ++ii) p = fmaf(gs[i0 + ii], We[(i0 + ii) * 128 + j], p);
        psum[kq][j] = p;
        __syncthreads();
        if (tid < HH) out[3 + j] = be[j] + psum[0][j] + psum[1][j] + psum[2][j] + psum[3][j];
    }
}

// ---------------- launch ----------------

extern "C" void kernel_launch(void* const* d_in, const int* in_sizes, int n_in,
                              void* d_out, int out_size, void* d_ws, size_t ws_size,
                              hipStream_t stream) {
    const float* x      = (const float*)d_in[0];
    const int*   hedges = (const int*)d_in[1];
    const float* Wi     = (const float*)d_in[2];
    const float* bi     = (const float*)d_in[3];
    const float* lnig   = (const float*)d_in[4];
    const float* lnib   = (const float*)d_in[5];
    const float* Wc     = (const float*)d_in[6];
    const float* bc     = (const float*)d_in[7];
    const float* Wq     = (const float*)d_in[8];
    const float* bq     = (const float*)d_in[9];
    const float* Wk     = (const float*)d_in[10];
    const float* bk     = (const float*)d_in[11];
    const float* Wv     = (const float*)d_in[12];
    const float* bv     = (const float*)d_in[13];
    const float* Wo     = (const float*)d_in[14];
    const float* bo     = (const float*)d_in[15];
    const float* n1g    = (const float*)d_in[16];
    const float* n1b    = (const float*)d_in[17];
    const float* n2g    = (const float*)d_in[18];
    const float* n2b    = (const float*)d_in[19];
    const float* Wf1    = (const float*)d_in[20];
    const float* bf1    = (const float*)d_in[21];
    const float* Wf2    = (const float*)d_in[22];
    const float* bf2    = (const float*)d_in[23];
    const float* Wh1    = (const float*)d_in[24];
    const float* bh1    = (const float*)d_in[25];
    const float* Wh2    = (const float*)d_in[26];
    const float* bh2    = (const float*)d_in[27];
    const float* Wh3    = (const float*)d_in[28];
    const float* bh3    = (const float*)d_in[29];
    const float* We     = (const float*)d_in[30];
    const float* be     = (const float*)d_in[31];

    float* ws = (float*)d_ws;
    float* h    = ws;                          // 25600
    float* h1   = ws + 25600;                  // 25600
    float* hc   = ws + 51200;                  // 25600
    float* Q    = ws + 76800;                  // 25600
    float* K    = ws + 102400;                 // 25600
    float* V    = ws + 128000;                 // 25600
    float* Gf   = ws + 153600;                 // 40000
    unsigned long long* bmT = (unsigned long long*)(ws + 193600);  // 51200 u64
    int*   lst  = (int*)(ws + 296000);         // 200*1024 ints
    int*   cntA = (int*)(ws + 500800);         // 256 ints

    k_prepA<<<NN, 1024, 0, stream>>>(hedges, bmT);
    k_prepB<<<NN, 1024, 0, stream>>>(bmT, x, Wi, bi, lnig, lnib, Wc, Gf, lst, cntA, h, hc);

    for (int l = 0; l < LL; ++l) {
        k_node1<<<NN, 1024, 0, stream>>>(h, hc, Gf, cntA,
            bc + l * HH,
            Wq + l * HH * HH, bq + l * HH,
            Wk + l * HH * HH, bk + l * HH,
            Wv + l * HH * HH, bv + l * HH,
            n1g + l * HH, n1b + l * HH,
            h1, Q, K, V);
        const float* WcN = (l + 1 < LL) ? (Wc + (l + 1) * HH * HH) : nullptr;
        k_edgefused<<<NN, 1024, 0, stream>>>(Q, K, V, hedges, lst, cntA, h1,
            Wo + l * HH * HH, bo + l * HH,
            Wf1 + l * HH * FFD, bf1 + l * FFD,
            Wf2 + l * FFD * HH, bf2 + l * HH,
            n2g + l * HH, n2b + l * HH,
            WcN, h, hc);
    }

    k_final4<<<4, 512, 0, stream>>>(h, Wh1, bh1, Wh2, bh2, Wh3, bh3, We, be, (float*)d_out);
}

// Round 8
// 187.430 us; speedup vs baseline: 1.3417x; 1.3417x over previous
//
#include <hip/hip_runtime.h>
#include <hip/hip_bf16.h>
#include <math.h>

#define NN 200
#define DD 8
#define HH 128
#define NHEAD 4
#define HDIM 32
#define LL 6
#define EE 16384
#define SS 8
#define FFD 512
#define W64 256                  // EE/64 bitmap words per node column

#define WSCALE 1048576.0f        // 2^20 fixed-point scale for LDS int attention atomics
#define WNORM  (1.0f/1048576.0f)
#define RSCALE 0.17677669529663687f   // 1/sqrt(32)

// ---------------- helpers ----------------

__device__ __forceinline__ float geluf(float x) {
    return 0.5f * x * (1.0f + erff(x * 0.70710678118654752f));
}
__device__ __forceinline__ float softplusf(float x) {
    return (x > 20.0f) ? x : log1pf(expf(x));
}
__device__ __forceinline__ void ln_reduce(const float* sv, const float* sv2, float* mred, int tid) {
    if (tid < 64) {
        float s1 = sv[tid] + sv[tid + 64];
        float s2 = sv2[tid] + sv2[tid + 64];
        #pragma unroll
        for (int m = 32; m > 0; m >>= 1) {
            s1 += __shfl_xor(s1, m);
            s2 += __shfl_xor(s2, m);
        }
        if (tid == 0) { mred[0] = s1 * (1.0f / HH); mred[1] = s2 * (1.0f / HH); }
    }
}

// ---------------- setup ----------------

// bitmap scatter (all 512 blocks) + embed h0/hc0 (blocks < 200)
__launch_bounds__(256)
__global__ void k_bitmapEmbed(const int* __restrict__ hedges, unsigned long long* __restrict__ bmT,
                              const float* __restrict__ x, const float* __restrict__ Wi,
                              const float* __restrict__ bi, const float* __restrict__ lnig,
                              const float* __restrict__ lnib, const float* __restrict__ Wc0,
                              float* __restrict__ h, float* __restrict__ hc) {
    int a = blockIdx.x, tid = threadIdx.x;
    // scatter this block's slice of memberships
    {
        int t = a * 256 + tid;
        int n = hedges[t];
        int e = t >> 3;
        atomicOr(&bmT[(e >> 6) * NN + n], 1ULL << (e & 63));
    }
    if (a >= NN) return;
    __shared__ float row[HH], sv[HH], sv2[HH], mred[2];
    __shared__ float psum[2][HH];
    float s = 0.0f;
    if (tid < HH) {
        s = bi[tid];
        #pragma unroll
        for (int d = 0; d < DD; ++d) s = fmaf(x[a * DD + d], Wi[d * HH + tid], s);
        sv[tid] = s; sv2[tid] = s * s;
    }
    __syncthreads();
    ln_reduce(sv, sv2, mred, tid);
    __syncthreads();
    if (tid < HH) {
        float mean = mred[0], var = mred[1] - mean * mean;
        float v = (s - mean) * rsqrtf(var + 1e-5f) * lnig[tid] + lnib[tid];
        float ge = geluf(v);
        int i2 = (tid >> 1) * 2;
        float div = expf((float)i2 * (-9.210340371976184f / 128.0f));
        float ang = (float)a * div;
        float pe = (tid & 1) ? cosf(ang) : sinf(ang);
        float hv = ge + pe;
        row[tid] = hv;
        h[a * HH + tid] = hv;
    }
    __syncthreads();
    {   // hc0 = row @ Wc0: 256 threads, 2-way split-K
        int kf = tid >> 7, j = tid & 127, k0 = kf * 64;
        float acc = 0.0f;
        #pragma unroll 8
        for (int kk = 0; kk < 64; ++kk) acc = fmaf(row[k0 + kk], Wc0[(k0 + kk) * HH + j], acc);
        psum[kf][j] = acc;
    }
    __syncthreads();
    if (tid < HH) hc[a * HH + tid] = psum[0][tid] + psum[1][tid];
}

// Per node a: float G row + member-edge list + count
__launch_bounds__(1024)
__global__ void k_prep(const unsigned long long* __restrict__ bmT,
                       float* __restrict__ Gf, int* __restrict__ lst, int* __restrict__ cntA) {
    __shared__ unsigned long long colA[W64];
    __shared__ int psG[4][256];
    __shared__ int wsum[4];
    int a = blockIdx.x, tid = threadIdx.x;
    if (tid < W64) colA[tid] = bmT[tid * NN + a];
    __syncthreads();
    {   // G row popcount, 4-way word split
        int q = tid >> 8, b = tid & 255;
        if (b < NN) {
            int acc = 0, w0 = q * 64;
            #pragma unroll 8
            for (int w = 0; w < 64; ++w) acc += __popcll(colA[w0 + w] & bmT[(w0 + w) * NN + b]);
            psG[q][b] = acc;
        }
    }
    // list extraction prefix-scan on first 256 threads
    unsigned long long w = 0ULL; int c = 0, incl = 0, lane = tid & 63, wid = tid >> 6;
    if (tid < W64) {
        w = colA[tid];
        c = __popcll(w);
        incl = c;
        #pragma unroll
        for (int m = 1; m < 64; m <<= 1) {
            int v = __shfl_up(incl, m);
            if (lane >= m) incl += v;
        }
        if (lane == 63) wsum[wid] = incl;
    }
    __syncthreads();
    if (tid == 0) {
        int ss = 0;
        #pragma unroll
        for (int i = 0; i < 4; ++i) { int v = wsum[i]; wsum[i] = ss; ss += v; }
        cntA[a] = ss;
    }
    if (tid < NN) Gf[a * NN + tid] = (float)(psG[0][tid] + psG[1][tid] + psG[2][tid] + psG[3][tid]);
    __syncthreads();
    if (tid < W64) {
        int base = wsum[wid] + incl - c;
        while (w) {
            int b = __ffsll((long long)w) - 1;
            w &= w - 1;
            lst[a * 1024 + base++] = tid * 64 + b;
        }
    }
}

// ---------------- layer kernels ----------------

// conv(G@hc) + LN1 + QKV.  grid: 200 x 1024, wide scalar phases + register prefetch
__launch_bounds__(1024)
__global__ void k_node1(const float* __restrict__ h, const float* __restrict__ hc,
                        const float* __restrict__ Gf, const int* __restrict__ cntA,
                        const float* __restrict__ bc,
                        const float* __restrict__ Wq, const float* __restrict__ bq,
                        const float* __restrict__ Wk, const float* __restrict__ bk,
                        const float* __restrict__ Wv, const float* __restrict__ bv,
                        const float* __restrict__ n1g, const float* __restrict__ n1b,
                        float* __restrict__ h1, float* __restrict__ Qo,
                        float* __restrict__ Ko, float* __restrict__ Vo) {
    int n = blockIdx.x, tid = threadIdx.x;
    int j = tid & 127, kq = tid >> 7;
    __shared__ float Gs[NN];
    __shared__ float row[HH], sv[HH], sv2[HH], mred[2];
    __shared__ float psA[8][HH], psB[8][HH], psC[8][HH];

    // ---- register prefetch (issue all independent loads up front)
    float hcv[25];
    {
        int m0 = kq * 25;
        #pragma unroll
        for (int mm = 0; mm < 25; ++mm) hcv[mm] = hc[(m0 + mm) * HH + j];
    }
    float hval = 0.0f, bcv = 0.0f, g1 = 0.0f, b1 = 0.0f;
    if (tid < HH) { hval = h[n * HH + tid]; bcv = bc[tid]; g1 = n1g[tid]; b1 = n1b[tid]; }
    float biasv = 0.0f;
    if (tid < 384) {
        int wh = tid >> 7;
        biasv = (wh == 0) ? bq[j] : (wh == 1) ? bk[j] : bv[j];
    }
    float cntn = fmaxf((float)cntA[n], 1.0f);
    if (tid < NN) Gs[tid] = Gf[n * NN + tid];
    __syncthreads();

    // conv: 8 kq x 25 rows, pure FMA from regs + LDS broadcast
    {
        float p = 0.0f; int m0 = kq * 25;
        #pragma unroll
        for (int mm = 0; mm < 25; ++mm) p = fmaf(Gs[m0 + mm], hcv[mm], p);
        psA[kq][j] = p;
    }
    __syncthreads();
    float val = 0.0f;
    if (tid < HH) {
        float acc = psA[0][tid] + psA[1][tid] + psA[2][tid] + psA[3][tid]
                  + psA[4][tid] + psA[5][tid] + psA[6][tid] + psA[7][tid];
        val = hval + acc / (8.0f * cntn) + bcv;
        sv[tid] = val; sv2[tid] = val * val;
    }
    __syncthreads();
    ln_reduce(sv, sv2, mred, tid);
    __syncthreads();
    if (tid < HH) {
        float mean = mred[0], var = mred[1] - mean * mean;
        float hv = (val - mean) * rsqrtf(var + 1e-5f) * g1 + b1;
        row[tid] = hv;
        h1[n * HH + tid] = hv;
    }
    __syncthreads();
    // QKV: 8 kq x 16 k, 3 accumulators
    {
        float pq = 0.0f, pk = 0.0f, pv = 0.0f; int k0 = kq * 16;
        #pragma unroll 4
        for (int kk = 0; kk < 16; ++kk) {
            float r = row[k0 + kk]; int idx = (k0 + kk) * HH + j;
            pq = fmaf(r, Wq[idx], pq);
            pk = fmaf(r, Wk[idx], pk);
            pv = fmaf(r, Wv[idx], pv);
        }
        psA[kq][j] = pq; psB[kq][j] = pk; psC[kq][j] = pv;
    }
    __syncthreads();
    if (tid < 384) {
        int wh = tid >> 7;
        const float (*pf)[HH] = (wh == 0) ? psA : (wh == 1) ? psB : psC;
        float acc = pf[0][j] + pf[1][j] + pf[2][j] + pf[3][j]
                  + pf[4][j] + pf[5][j] + pf[6][j] + pf[7][j];
        float o = biasv + acc;
        if (wh == 0)      Qo[n * HH + j] = o;
        else if (wh == 1) Ko[n * HH + j] = o;
        else              Vo[n * HH + j] = o;
    }
}

// attention + Wo + FFN + LN2 + next-layer hc.  grid: 200 x 1024
__launch_bounds__(1024)
__global__ void k_edgefused(const float* __restrict__ Q, const float* __restrict__ K,
                            const float* __restrict__ V, const int* __restrict__ hedges,
                            const int* __restrict__ lst, const int* __restrict__ cntA,
                            const float* __restrict__ h1,
                            const float* __restrict__ Wo, const float* __restrict__ bo,
                            const float* __restrict__ Wf1, const float* __restrict__ bf1,
                            const float* __restrict__ Wf2, const float* __restrict__ bf2,
                            const float* __restrict__ n2g, const float* __restrict__ n2b,
                            const float* __restrict__ WcN,
                            float* __restrict__ h, float* __restrict__ hc) {
    __shared__ float Ts[NHEAD * NN];
    __shared__ int   Wrow[NHEAD * NN];
    __shared__ float Qs[HH];
    __shared__ float psum[8][HH];
    __shared__ float psF[2][FFD];
    __shared__ float ts[FFD];
    __shared__ float sv[HH], sv2[HH], mred[2];
    __shared__ float aggs[HH], h2s[HH], rowN[HH];

    int a = blockIdx.x, tid = threadIdx.x;
    int j = tid & 127, kq = tid >> 7;
    int cnt = cntA[a];
    float cntn = fmaxf((float)cnt, 1.0f);
    int ntask = cnt * NHEAD;
    const int* lstA = lst + a * 1024;

    // ---- register prefetch
    float h1v = 0.0f, bov = 0.0f, bf2v = 0.0f, n2gv = 0.0f, n2bv = 0.0f;
    if (tid < HH) {
        h1v = h1[a * HH + tid]; bov = bo[tid];
        bf2v = bf2[tid]; n2gv = n2g[tid]; n2bv = n2b[tid];
    }
    float bf1v = 0.0f;
    if (tid < FFD) bf1v = bf1[tid];
    // member-edge chains for up to 4 strip-mine iterations
    int4 pe0[4], pe1[4];
    #pragma unroll
    for (int it = 0; it < 4; ++it) {
        int t = tid + it * 1024;
        pe0[it] = make_int4(0, 0, 0, 0); pe1[it] = make_int4(0, 0, 0, 0);
        if (t < ntask) {
            int e = lstA[t >> 2];
            pe0[it] = ((const int4*)hedges)[e * 2];
            pe1[it] = ((const int4*)hedges)[e * 2 + 1];
        }
    }
    // K row for logits (independent of Qs)
    int lb = tid & 255, lh = tid >> 8;
    float4 kv[8];
    if (lb < NN) {
        const float4* kp4 = (const float4*)(K + lb * HH + lh * HDIM);
        #pragma unroll
        for (int u = 0; u < 8; ++u) kv[u] = kp4[u];
    }
    if (tid < HH) Qs[tid] = Q[a * HH + tid];
    if (tid < NHEAD * NN) Wrow[tid] = 0;
    __syncthreads();

    // logits Ts[h][b] = (q_a[h].k_b[h]) * RSCALE
    if (lb < NN) {
        const float4* qp4 = (const float4*)(Qs + lh * HDIM);
        float acc = 0.0f;
        #pragma unroll
        for (int u = 0; u < 8; ++u) {
            float4 qv = qp4[u];
            acc += qv.x * kv[u].x + qv.y * kv[u].y + qv.z * kv[u].z + qv.w * kv[u].w;
        }
        Ts[lh * NN + lb] = acc * RSCALE;
    }
    __syncthreads();

    // phase A: per (member-edge, head) softmax -> LDS int scatter
    #pragma unroll
    for (int it = 0; it < 4; ++it) {
        int t = tid + it * 1024;
        if (t < ntask) {
            int hh = t & 3;
            int4 e0 = pe0[it], e1 = pe1[it];
            const float* Tr = Ts + hh * NN;
            float l0 = Tr[e0.x], l1 = Tr[e0.y], l2 = Tr[e0.z], l3 = Tr[e0.w];
            float l4 = Tr[e1.x], l5 = Tr[e1.y], l6 = Tr[e1.z], l7 = Tr[e1.w];
            float mx = fmaxf(fmaxf(fmaxf(l0, l1), fmaxf(l2, l3)),
                             fmaxf(fmaxf(l4, l5), fmaxf(l6, l7)));
            l0 = __expf(l0 - mx); l1 = __expf(l1 - mx); l2 = __expf(l2 - mx); l3 = __expf(l3 - mx);
            l4 = __expf(l4 - mx); l5 = __expf(l5 - mx); l6 = __expf(l6 - mx); l7 = __expf(l7 - mx);
            float inv = WSCALE / (l0 + l1 + l2 + l3 + l4 + l5 + l6 + l7);
            int* Wr = Wrow + hh * NN;
            atomicAdd(&Wr[e0.x], __float2int_rn(l0 * inv));
            atomicAdd(&Wr[e0.y], __float2int_rn(l1 * inv));
            atomicAdd(&Wr[e0.z], __float2int_rn(l2 * inv));
            atomicAdd(&Wr[e0.w], __float2int_rn(l3 * inv));
            atomicAdd(&Wr[e1.x], __float2int_rn(l4 * inv));
            atomicAdd(&Wr[e1.y], __float2int_rn(l5 * inv));
            atomicAdd(&Wr[e1.z], __float2int_rn(l6 * inv));
            atomicAdd(&Wr[e1.w], __float2int_rn(l7 * inv));
        }
    }
    __syncthreads();

    // phase B: agg = Wrow@V, 8 kq x 25 b  (j = hh*32+d)
    {
        int hh = (tid >> 5) & 3;
        float acc = 0.0f; int b0 = kq * 25;
        #pragma unroll 5
        for (int bb = 0; bb < 25; ++bb) {
            int b = b0 + bb;
            acc = fmaf((float)Wrow[hh * NN + b], V[b * HH + j], acc);
        }
        psum[kq][j] = acc;
    }
    __syncthreads();
    if (tid < HH) {
        float acc = psum[0][tid] + psum[1][tid] + psum[2][tid] + psum[3][tid]
                  + psum[4][tid] + psum[5][tid] + psum[6][tid] + psum[7][tid];
        aggs[tid] = acc * WNORM / cntn;
    }
    __syncthreads();
    // Wo GEMV: 8 kq x 16
    {
        float p = 0.0f; int k0 = kq * 16;
        #pragma unroll 8
        for (int kk = 0; kk < 16; ++kk) p = fmaf(aggs[k0 + kk], Wo[(k0 + kk) * HH + j], p);
        psum[kq][j] = p;
    }
    __syncthreads();
    if (tid < HH) {
        float acc = psum[0][tid] + psum[1][tid] + psum[2][tid] + psum[3][tid]
                  + psum[4][tid] + psum[5][tid] + psum[6][tid] + psum[7][tid];
        h2s[tid] = h1v + bov + acc;
    }
    __syncthreads();
    // FFN1: 512 outputs x 2-way split-K (chain 64)
    {
        int f = tid & 511, hf = tid >> 9;
        float tval = 0.0f; int k0 = hf * 64;
        #pragma unroll 8
        for (int kk = 0; kk < 64; ++kk) tval = fmaf(h2s[k0 + kk], Wf1[(k0 + kk) * FFD + f], tval);
        psF[hf][f] = tval;
    }
    __syncthreads();
    if (tid < FFD) ts[tid] = geluf(bf1v + psF[0][tid] + psF[1][tid]);
    __syncthreads();
    // FFN2: 8 kq x 64
    {
        float p = 0.0f; int f0 = kq * 64;
        #pragma unroll 8
        for (int ff = 0; ff < 64; ++ff) p = fmaf(ts[f0 + ff], Wf2[(f0 + ff) * HH + j], p);
        psum[kq][j] = p;
    }
    __syncthreads();
    float o = 0.0f;
    if (tid < HH) {
        float acc = psum[0][tid] + psum[1][tid] + psum[2][tid] + psum[3][tid]
                  + psum[4][tid] + psum[5][tid] + psum[6][tid] + psum[7][tid];
        o = h2s[tid] + bf2v + acc;
        sv[tid] = o; sv2[tid] = o * o;
    }
    __syncthreads();
    ln_reduce(sv, sv2, mred, tid);
    __syncthreads();
    if (tid < HH) {
        float mean = mred[0], var = mred[1] - mean * mean;
        float hv = (o - mean) * rsqrtf(var + 1e-5f) * n2gv + n2bv;
        rowN[tid] = hv;
        h[a * HH + tid] = hv;
    }
    __syncthreads();
    if (WcN) {
        float p = 0.0f; int k0 = kq * 16;
        #pragma unroll 8
        for (int kk = 0; kk < 16; ++kk) p = fmaf(rowN[k0 + kk], WcN[(k0 + kk) * HH + j], p);
        psum[kq][j] = p;
        __syncthreads();
        if (tid < HH) {
            float acc = psum[0][tid] + psum[1][tid] + psum[2][tid] + psum[3][tid]
                      + psum[4][tid] + psum[5][tid] + psum[6][tid] + psum[7][tid];
            hc[a * HH + tid] = acc;
        }
    }
}

// Pool + heads + emb, 4 blocks x 512
__launch_bounds__(512)
__global__ void k_final4(const float* __restrict__ h,
                         const float* __restrict__ Wh1, const float* __restrict__ bh1,
                         const float* __restrict__ Wh2, const float* __restrict__ bh2,
                         const float* __restrict__ Wh3, const float* __restrict__ bh3,
                         const float* __restrict__ We, const float* __restrict__ be,
                         float* __restrict__ out) {
    __shared__ float gs[384];
    __shared__ float pm[4][HH], px[4][HH];
    __shared__ float psum[4][HH];
    __shared__ float t1s[HH];
    __shared__ float t2s[64];
    int tid = threadIdx.x, j = tid & 127, kq = tid >> 7, kb = blockIdx.x;
    {
        float sm = 0.0f, mx = -3.4e38f;
        for (int r = 0; r < 50; ++r) {
            float v = h[(kq * 50 + r) * HH + j];
            sm += v; mx = fmaxf(mx, v);
        }
        pm[kq][j] = sm; px[kq][j] = mx;
    }
    __syncthreads();
    if (tid < HH) {
        float s = pm[0][j] + pm[1][j] + pm[2][j] + pm[3][j];
        float m = fmaxf(fmaxf(px[0][j], px[1][j]), fmaxf(px[2][j], px[3][j]));
        gs[j] = s * (1.0f / NN); gs[HH + j] = m; gs[2 * HH + j] = s;
    }
    __syncthreads();
    if (kb < 3) {
        float p = 0.0f;
        int i0 = kq * 96;
        #pragma unroll 8
        for (int ii = 0; ii < 96; ++ii) p = fmaf(gs[i0 + ii], Wh1[kb * 49152 + (i0 + ii) * 128 + j], p);
        psum[kq][j] = p;
        __syncthreads();
        if (tid < HH) t1s[j] = geluf(bh1[kb * 128 + j] + psum[0][j] + psum[1][j] + psum[2][j] + psum[3][j]);
        __syncthreads();
        if (tid < 256) {
            int o = tid & 63, sc = tid >> 6;
            float p2 = 0.0f;
            int i0b = sc * 32;
            #pragma unroll 8
            for (int ii = 0; ii < 32; ++ii) p2 = fmaf(t1s[i0b + ii], Wh2[kb * 8192 + (i0b + ii) * 64 + o], p2);
            psum[sc][o] = p2;
        }
        __syncthreads();
        if (tid < 64) t2s[tid] = geluf(bh2[kb * 64 + tid] + psum[0][tid] + psum[1][tid] + psum[2][tid] + psum[3][tid]);
        __syncthreads();
        if (tid < 64) {
            float v = t2s[tid] * Wh3[kb * 64 + tid];
            #pragma unroll
            for (int m = 32; m > 0; m >>= 1) v += __shfl_xor(v, m);
            if (tid == 0) {
                float acc = v + bh3[kb];
                float r;
                if (kb == 0)      r = softplusf(acc) + 1.0f;
                else if (kb == 1) r = 1.0f / (1.0f + expf(-acc));
                else              r = softplusf(acc);
                out[kb] = r;
            }
        }
    } else {
        float p = 0.0f;
        int i0 = kq * 96;
        #pragma unroll 8
        for (int ii = 0; ii < 96; ++ii) p = fmaf(gs[i0 + ii], We[(i0 + ii) * 128 + j], p);
        psum[kq][j] = p;
        __syncthreads();
        if (tid < HH) out[3 + j] = be[j] + psum[0][j] + psum[1][j] + psum[2][j] + psum[3][j];
    }
}

// ---------------- launch ----------------

extern "C" void kernel_launch(void* const* d_in, const int* in_sizes, int n_in,
                              void* d_out, int out_size, void* d_ws, size_t ws_size,
                              hipStream_t stream) {
    const float* x      = (const float*)d_in[0];
    const int*   hedges = (const int*)d_in[1];
    const float* Wi     = (const float*)d_in[2];
    const float* bi     = (const float*)d_in[3];
    const float* lnig   = (const float*)d_in[4];
    const float* lnib   = (const float*)d_in[5];
    const float* Wc     = (const float*)d_in[6];
    const float* bc     = (const float*)d_in[7];
    const float* Wq     = (const float*)d_in[8];
    const float* bq     = (const float*)d_in[9];
    const float* Wk     = (const float*)d_in[10];
    const float* bk     = (const float*)d_in[11];
    const float* Wv     = (const float*)d_in[12];
    const float* bv     = (const float*)d_in[13];
    const float* Wo     = (const float*)d_in[14];
    const float* bo     = (const float*)d_in[15];
    const float* n1g    = (const float*)d_in[16];
    const float* n1b    = (const float*)d_in[17];
    const float* n2g    = (const float*)d_in[18];
    const float* n2b    = (const float*)d_in[19];
    const float* Wf1    = (const float*)d_in[20];
    const float* bf1    = (const float*)d_in[21];
    const float* Wf2    = (const float*)d_in[22];
    const float* bf2    = (const float*)d_in[23];
    const float* Wh1    = (const float*)d_in[24];
    const float* bh1    = (const float*)d_in[25];
    const float* Wh2    = (const float*)d_in[26];
    const float* bh2    = (const float*)d_in[27];
    const float* Wh3    = (const float*)d_in[28];
    const float* bh3    = (const float*)d_in[29];
    const float* We     = (const float*)d_in[30];
    const float* be     = (const float*)d_in[31];

    float* ws = (float*)d_ws;
    float* h    = ws;                          // 25600
    float* h1   = ws + 25600;                  // 25600
    float* hc   = ws + 51200;                  // 25600
    float* Q    = ws + 76800;                  // 25600
    float* K    = ws + 102400;                 // 25600
    float* V    = ws + 128000;                 // 25600
    float* Gf   = ws + 153600;                 // 40000
    unsigned long long* bmT = (unsigned long long*)(ws + 193600);  // 51200 u64
    int*   lst  = (int*)(ws + 296000);         // 200*1024 ints
    int*   cntA = (int*)(ws + 500800);         // 256 ints

    hipMemsetAsync(bmT, 0, (size_t)W64 * NN * sizeof(unsigned long long), stream);
    k_bitmapEmbed<<<512, 256, 0, stream>>>(hedges, bmT, x, Wi, bi, lnig, lnib, Wc, h, hc);
    k_prep<<<NN, 1024, 0, stream>>>(bmT, Gf, lst, cntA);

    for (int l = 0; l < LL; ++l) {
        k_node1<<<NN, 1024, 0, stream>>>(h, hc, Gf, cntA,
            bc + l * HH,
            Wq + l * HH * HH, bq + l * HH,
            Wk + l * HH * HH, bk + l * HH,
            Wv + l * HH * HH, bv + l * HH,
            n1g + l * HH, n1b + l * HH,
            h1, Q, K, V);
        const float* WcN = (l + 1 < LL) ? (Wc + (l + 1) * HH * HH) : nullptr;
        k_edgefused<<<NN, 1024, 0, stream>>>(Q, K, V, hedges, lst, cntA, h1,
            Wo + l * HH * HH, bo + l * HH,
            Wf1 + l * HH * FFD, bf1 + l * FFD,
            Wf2 + l * FFD * HH, bf2 + l * HH,
            n2g + l * HH, n2b + l * HH,
            WcN, h, hc);
    }

    k_final4<<<4, 512, 0, stream>>>(h, Wh1, bh1, Wh2, bh2, Wh3, bh3, We, be, (float*)d_out);
}